// Round 9
// baseline (384.314 us; speedup 1.0000x reference)
//
#include <hip/hip_runtime.h>
#include <math.h>

// Problem constants (from reference)
#define NN 50000
#define NE 800000
#define NFEAT 128
#define NHID 64
#define NCLASS 16
#define NB_SCAN ((NN + 255) / 256)  // 196
#define ROWS_PER_GRP 6250           // NN / 8 XCD row-groups (scatter)
#define GB ((NN + 63) / 64)         // 782 row-tiles
#define SCHUNKS 392                 // scatter chunks; grid = 8*392
#define CHUNK16 ((NN + 15) / 16)    // 3125 16-row chunks (spmm)
#define CPX ((CHUNK16 + 3) / 4)     // 782 chunks per XCD

struct alignas(8) Edge {
    int c;
    float w;
};

// fp32 <-> bf16 helpers (RNE round)
__device__ inline unsigned short f2bf(float f) {
    unsigned u = __builtin_bit_cast(unsigned, f);
    u += 0x7fffu + ((u >> 16) & 1u);
    return (unsigned short)(u >> 16);
}
__device__ inline float bf2f(unsigned short h) {
    return __builtin_bit_cast(float, (unsigned)h << 16);
}

// ---------------- CSR build ----------------

// Degree histogram; atomicAdd's return value IS the edge's rank within its row.
__global__ __launch_bounds__(256) void hist_rank_kernel(const int* __restrict__ erow,
                                                        int* __restrict__ deg,
                                                        unsigned* __restrict__ rr, int E) {
    int e = blockIdx.x * 256 + threadIdx.x;
    if (e < E) {
        int r = erow[e];
        int k = atomicAdd(&deg[r], 1);
        rr[e] = ((unsigned)r << 16) | (unsigned)k;
    }
}

__global__ __launch_bounds__(256) void scan_sum_kernel(const int* __restrict__ deg,
                                                       int* __restrict__ blocksum, int n) {
    __shared__ int s[256];
    const int t = threadIdx.x;
    int i = blockIdx.x * 256 + t;
    s[t] = (i < n) ? deg[i] : 0;
    __syncthreads();
#pragma unroll
    for (int off = 128; off > 0; off >>= 1) {
        if (t < off) s[t] += s[t + off];
        __syncthreads();
    }
    if (t == 0) blocksum[blockIdx.x] = s[0];
}

__global__ __launch_bounds__(256) void scan_top_kernel(int* __restrict__ blocksum, int nb) {
    __shared__ int s[256];
    const int t = threadIdx.x;
    int v = (t < nb) ? blocksum[t] : 0;
    s[t] = v;
    __syncthreads();
    for (int off = 1; off < 256; off <<= 1) {
        int u = (t >= off) ? s[t - off] : 0;
        __syncthreads();
        s[t] += u;
        __syncthreads();
    }
    if (t < nb) blocksum[t] = s[t] - v;  // exclusive
}

__global__ __launch_bounds__(256) void scan_final_kernel(const int* __restrict__ deg,
                                                         const int* __restrict__ blocksum,
                                                         int* __restrict__ row_ptr, int n) {
    __shared__ int s[256];
    const int t = threadIdx.x;
    int i = blockIdx.x * 256 + t;
    int d = (i < n) ? deg[i] : 0;
    s[t] = d;
    __syncthreads();
    for (int off = 1; off < 256; off <<= 1) {
        int u = (t >= off) ? s[t - off] : 0;
        __syncthreads();
        s[t] += u;
        __syncthreads();
    }
    int excl = blocksum[blockIdx.x] + s[t] - d;
    if (i < n) {
        row_ptr[i] = excl;
        if (i == n - 1) row_ptr[n] = excl + d;
    }
}

// Atomic-free scatter: pos = row_ptr[row] + rank. XCD-partitioned by destination.
__global__ __launch_bounds__(256) void scatter_rank_kernel(const unsigned* __restrict__ rr,
                                                           const int* __restrict__ ecol,
                                                           const float* __restrict__ ew,
                                                           const int* __restrict__ row_ptr,
                                                           Edge* __restrict__ pairs, int E) {
    const int g = blockIdx.x & 7;
    const int chunk = blockIdx.x >> 3;
    const int CH = (E + SCHUNKS - 1) / SCHUNKS;
    const int lo = chunk * CH;
    const int hi = (lo + CH < E) ? lo + CH : E;
    for (int e = lo + threadIdx.x; e < hi; e += 256) {
        unsigned v = rr[e];
        int r = (int)(v >> 16);
        if (r / ROWS_PER_GRP == g) {
            int pos = row_ptr[r] + (int)(v & 0xffffu);
            Edge p;
            p.c = ecol[e];
            p.w = ew[e];
            pairs[pos] = p;
        }
    }
}

// ---------------- Tiled GEMM: out[M,64] = act(in[M,K]) @ W[K,64] ----------------
template <int K, bool RELU_IN>
__global__ __launch_bounds__(256) void gemm64_kernel(const float* __restrict__ in,
                                                     const float* __restrict__ Wg,
                                                     unsigned short* __restrict__ outb, int M) {
    constexpr int KC = 64;
    __shared__ float xs[KC][68];
    __shared__ float Ws[KC][64];
    const int t = threadIdx.x;
    const int tx = t % 16;
    const int ty = t / 16;
    const int r0 = blockIdx.x * 64;

    float acc[4][4];
#pragma unroll
    for (int i = 0; i < 4; i++)
#pragma unroll
        for (int j = 0; j < 4; j++) acc[i][j] = 0.f;

    for (int k0 = 0; k0 < K; k0 += KC) {
        for (int i = t * 4; i < KC * 64; i += 1024) {
            *(float4*)&Ws[i / 64][i % 64] = *(const float4*)&Wg[(size_t)k0 * 64 + i];
        }
        {
            const int r = t / 4;
            const int q = t % 4;
            const int gr = r0 + r;
#pragma unroll
            for (int i = 0; i < 4; i++) {
                int k = q * 16 + i * 4;
                float4 v;
                if (gr < M)
                    v = *(const float4*)&in[(size_t)gr * K + k0 + k];
                else
                    v = make_float4(0.f, 0.f, 0.f, 0.f);
                if (RELU_IN) {
                    v.x = fmaxf(v.x, 0.f);
                    v.y = fmaxf(v.y, 0.f);
                    v.z = fmaxf(v.z, 0.f);
                    v.w = fmaxf(v.w, 0.f);
                }
                xs[k + 0][r] = v.x;
                xs[k + 1][r] = v.y;
                xs[k + 2][r] = v.z;
                xs[k + 3][r] = v.w;
            }
        }
        __syncthreads();
#pragma unroll 8
        for (int k = 0; k < KC; k++) {
            float4 xv = *(const float4*)&xs[k][ty * 4];
            float4 wv = *(const float4*)&Ws[k][tx * 4];
            acc[0][0] += xv.x * wv.x; acc[0][1] += xv.x * wv.y;
            acc[0][2] += xv.x * wv.z; acc[0][3] += xv.x * wv.w;
            acc[1][0] += xv.y * wv.x; acc[1][1] += xv.y * wv.y;
            acc[1][2] += xv.y * wv.z; acc[1][3] += xv.y * wv.w;
            acc[2][0] += xv.z * wv.x; acc[2][1] += xv.z * wv.y;
            acc[2][2] += xv.z * wv.z; acc[2][3] += xv.z * wv.w;
            acc[3][0] += xv.w * wv.x; acc[3][1] += xv.w * wv.y;
            acc[3][2] += xv.w * wv.z; acc[3][3] += xv.w * wv.w;
        }
        __syncthreads();
    }
#pragma unroll
    for (int i = 0; i < 4; i++) {
        int r = r0 + ty * 4 + i;
        if (r < M) {
            ushort4 u;
            u.x = f2bf(acc[i][0]);
            u.y = f2bf(acc[i][1]);
            u.z = f2bf(acc[i][2]);
            u.w = f2bf(acc[i][3]);
            *(ushort4*)&outb[(size_t)r * 64 + tx * 4] = u;
        }
    }
}

// ---------------- Small GEMM (layer 5): out[M,16] = relu(in[M,64]) @ W[64,16] ----------------
template <int K, int NOUT, int RPT, bool RELU_IN>
__global__ __launch_bounds__(256) void gemm_kernel(const float* __restrict__ in,
                                                   const float* __restrict__ Wg,
                                                   float* __restrict__ out, int M) {
    __shared__ float Wl[K * NOUT];
    for (int i = threadIdx.x * 4; i < K * NOUT; i += 256 * 4) {
        *(float4*)&Wl[i] = *(const float4*)&Wg[i];
    }
    __syncthreads();

    constexpr int GROUPS = 256 / NOUT;
    constexpr int RPB = GROUPS * RPT;
    const int col = threadIdx.x % NOUT;
    const int grp = threadIdx.x / NOUT;
    const int r = blockIdx.x * RPB + grp * RPT;
    if (r >= M) return;

    float acc[RPT];
#pragma unroll
    for (int j = 0; j < RPT; j++) acc[j] = 0.f;

    const float* pr = in + (size_t)r * K;
#pragma unroll 2
    for (int k = 0; k < K; k += 4) {
        float w0 = Wl[(k + 0) * NOUT + col];
        float w1 = Wl[(k + 1) * NOUT + col];
        float w2 = Wl[(k + 2) * NOUT + col];
        float w3 = Wl[(k + 3) * NOUT + col];
#pragma unroll
        for (int j = 0; j < RPT; j++) {
            float4 xv = *(const float4*)(pr + j * K + k);
            if (RELU_IN) {
                xv.x = fmaxf(xv.x, 0.f);
                xv.y = fmaxf(xv.y, 0.f);
                xv.z = fmaxf(xv.z, 0.f);
                xv.w = fmaxf(xv.w, 0.f);
            }
            acc[j] += xv.x * w0;
            acc[j] += xv.y * w1;
            acc[j] += xv.z * w2;
            acc[j] += xv.w * w3;
        }
    }
#pragma unroll
    for (int j = 0; j < RPT; j++) {
        if (r + j < M) out[(size_t)(r + j) * NOUT + col] = acc[j];
    }
}

// ---------------- XCD-pinned feature-split SpMM (F=64, bf16 gather) ----------------
// blockIdx%8 -> XCD (round-robin dispatch). XCDs 0-3 compute feature cols 0-31 for all
// rows; XCDs 4-7 compute cols 32-63. Each XCD's gather footprint = 3.2 MB < 4 MB L2
// (round-6's split failed because both halves ran on every XCD -> 6.4 MB).
// 16 lanes/row x ushort2 = exactly one aligned 64 B line per edge-gather. Unroll-8.
__global__ __launch_bounds__(256) void spmm64x_kernel(const unsigned short* __restrict__ tmpb,
                                                      const int* __restrict__ row_ptr,
                                                      const Edge* __restrict__ pairs,
                                                      const float* __restrict__ bias,
                                                      float* __restrict__ e_out, int M) {
    const int g = blockIdx.x & 7;
    const int half = g >> 2;
    const int cc = (blockIdx.x >> 3) * 4 + (g & 3);  // 16-row chunk id
    if (cc >= CHUNK16) return;
    const int t = threadIdx.x;
    const int r = cc * 16 + (t >> 4);
    if (r >= M) return;
    const int f2 = half * 32 + (t & 15) * 2;

    int e = row_ptr[r];
    const int end = row_ptr[r + 1];
    float a0 = 0.f, a1 = 0.f;
    for (; e + 7 < end; e += 8) {
        Edge p0 = pairs[e + 0], p1 = pairs[e + 1], p2 = pairs[e + 2], p3 = pairs[e + 3];
        Edge p4 = pairs[e + 4], p5 = pairs[e + 5], p6 = pairs[e + 6], p7 = pairs[e + 7];
        unsigned g0 = *(const unsigned*)&tmpb[(size_t)p0.c * 64 + f2];
        unsigned g1 = *(const unsigned*)&tmpb[(size_t)p1.c * 64 + f2];
        unsigned g2 = *(const unsigned*)&tmpb[(size_t)p2.c * 64 + f2];
        unsigned g3 = *(const unsigned*)&tmpb[(size_t)p3.c * 64 + f2];
        unsigned g4 = *(const unsigned*)&tmpb[(size_t)p4.c * 64 + f2];
        unsigned g5 = *(const unsigned*)&tmpb[(size_t)p5.c * 64 + f2];
        unsigned g6 = *(const unsigned*)&tmpb[(size_t)p6.c * 64 + f2];
        unsigned g7 = *(const unsigned*)&tmpb[(size_t)p7.c * 64 + f2];
        a0 += p0.w * bf2f((unsigned short)(g0 & 0xffffu));
        a1 += p0.w * bf2f((unsigned short)(g0 >> 16));
        a0 += p1.w * bf2f((unsigned short)(g1 & 0xffffu));
        a1 += p1.w * bf2f((unsigned short)(g1 >> 16));
        a0 += p2.w * bf2f((unsigned short)(g2 & 0xffffu));
        a1 += p2.w * bf2f((unsigned short)(g2 >> 16));
        a0 += p3.w * bf2f((unsigned short)(g3 & 0xffffu));
        a1 += p3.w * bf2f((unsigned short)(g3 >> 16));
        a0 += p4.w * bf2f((unsigned short)(g4 & 0xffffu));
        a1 += p4.w * bf2f((unsigned short)(g4 >> 16));
        a0 += p5.w * bf2f((unsigned short)(g5 & 0xffffu));
        a1 += p5.w * bf2f((unsigned short)(g5 >> 16));
        a0 += p6.w * bf2f((unsigned short)(g6 & 0xffffu));
        a1 += p6.w * bf2f((unsigned short)(g6 >> 16));
        a0 += p7.w * bf2f((unsigned short)(g7 & 0xffffu));
        a1 += p7.w * bf2f((unsigned short)(g7 >> 16));
    }
    for (; e < end; e++) {
        Edge p = pairs[e];
        unsigned gg = *(const unsigned*)&tmpb[(size_t)p.c * 64 + f2];
        a0 += p.w * bf2f((unsigned short)(gg & 0xffffu));
        a1 += p.w * bf2f((unsigned short)(gg >> 16));
    }
    float2 v;
    v.x = a0 + bias[f2];
    v.y = a1 + bias[f2 + 1];
    *(float2*)&e_out[(size_t)r * 64 + f2] = v;
}

// ---------------- SpMM (F=16, fp32) fused with log_softmax ----------------
__global__ __launch_bounds__(256) void spmm16_lsm_kernel(const float* __restrict__ tmp,
                                                         const int* __restrict__ row_ptr,
                                                         const Edge* __restrict__ pairs,
                                                         const float* __restrict__ bias,
                                                         float* __restrict__ e5,
                                                         float* __restrict__ out0, int M) {
    const int f = threadIdx.x & 15;
    const int rl = threadIdx.x >> 4;
    const int r = blockIdx.x * 16 + rl;
    if (r >= M) return;

    const int start = row_ptr[r];
    const int end = row_ptr[r + 1];
    float acc = 0.f;
    int e = start;
    for (; e + 3 < end; e += 4) {
        Edge p0 = pairs[e + 0], p1 = pairs[e + 1], p2 = pairs[e + 2], p3 = pairs[e + 3];
        acc += p0.w * tmp[(size_t)p0.c * 16 + f];
        acc += p1.w * tmp[(size_t)p1.c * 16 + f];
        acc += p2.w * tmp[(size_t)p2.c * 16 + f];
        acc += p3.w * tmp[(size_t)p3.c * 16 + f];
    }
    for (; e < end; e++) {
        Edge p = pairs[e];
        acc += p.w * tmp[(size_t)p.c * 16 + f];
    }
    float v = acc + bias[f];
    e5[(size_t)r * 16 + f] = v;

    float m = v;
#pragma unroll
    for (int off = 1; off < 16; off <<= 1) m = fmaxf(m, __shfl_xor(m, off, 16));
    float s = expf(v - m);
#pragma unroll
    for (int off = 1; off < 16; off <<= 1) s += __shfl_xor(s, off, 16);
    float ls = logf(s);
    out0[(size_t)r * 16 + f] = v - m - ls;
}

// ---------------- launch ----------------

extern "C" void kernel_launch(void* const* d_in, const int* in_sizes, int n_in,
                              void* d_out, int out_size, void* d_ws, size_t ws_size,
                              hipStream_t stream) {
    const float* x = (const float*)d_in[0];
    const int* erow = (const int*)d_in[1];
    const int* ecol = (const int*)d_in[2];
    const float* ew = (const float*)d_in[3];
    const float* W1 = (const float*)d_in[4];
    const float* b1 = (const float*)d_in[5];
    const float* W2 = (const float*)d_in[6];
    const float* b2 = (const float*)d_in[7];
    const float* W3 = (const float*)d_in[8];
    const float* b3 = (const float*)d_in[9];
    const float* W4 = (const float*)d_in[10];
    const float* b4 = (const float*)d_in[11];
    const float* W5 = (const float*)d_in[12];
    const float* b5 = (const float*)d_in[13];

    // Output layout: log_softmax(e5), e1, e2, e3, e4, e5
    float* out0 = (float*)d_out;
    float* e1 = out0 + (size_t)NN * NCLASS;
    float* e2 = e1 + (size_t)NN * NHID;
    float* e3 = e2 + (size_t)NN * NHID;
    float* e4 = e3 + (size_t)NN * NHID;
    float* e5 = e4 + (size_t)NN * NHID;

    // Workspace layout
    char* ws = (char*)d_ws;
    unsigned short* tmpb = (unsigned short*)ws; ws += (size_t)NN * NHID * 2;   // 6.4 MB
    float* tmp32 = (float*)ws; ws += (size_t)NN * NCLASS * sizeof(float);      // 3.2 MB
    int* deg = (int*)ws;       ws += ((size_t)NN * 4 + 255) / 256 * 256;       // zeroed below
    int* row_ptr = (int*)ws;   ws += ((size_t)(NN + 1) * 4 + 255) / 256 * 256;
    int* blocksum = (int*)ws;  ws += ((size_t)NB_SCAN * 4 + 255) / 256 * 256;
    unsigned* rr = (unsigned*)ws; ws += (size_t)NE * 4;                        // 3.2 MB
    Edge* pairs = (Edge*)ws;   ws += (size_t)NE * sizeof(Edge);                // 6.4 MB

    const int SPMM_GRID = ((CHUNK16 + 3) / 4) * 8;  // 6256 blocks (16 rows x half each)

    // ---- CSR build: hist+rank, scans, atomic-free partitioned scatter ----
    hipMemsetAsync(deg, 0, (size_t)NN * 4, stream);
    hist_rank_kernel<<<(NE + 255) / 256, 256, 0, stream>>>(erow, deg, rr, NE);
    scan_sum_kernel<<<NB_SCAN, 256, 0, stream>>>(deg, blocksum, NN);
    scan_top_kernel<<<1, 256, 0, stream>>>(blocksum, NB_SCAN);
    scan_final_kernel<<<NB_SCAN, 256, 0, stream>>>(deg, blocksum, row_ptr, NN);
    scatter_rank_kernel<<<8 * SCHUNKS, 256, 0, stream>>>(rr, ecol, ew, row_ptr, pairs, NE);

    // ---- Layer 1 ----
    gemm64_kernel<NFEAT, false><<<GB, 256, 0, stream>>>(x, W1, tmpb, NN);
    spmm64x_kernel<<<SPMM_GRID, 256, 0, stream>>>(tmpb, row_ptr, pairs, b1, e1, NN);

    // ---- Layer 2 (reads e1 with relu-on-load) ----
    gemm64_kernel<NHID, true><<<GB, 256, 0, stream>>>(e1, W2, tmpb, NN);
    spmm64x_kernel<<<SPMM_GRID, 256, 0, stream>>>(tmpb, row_ptr, pairs, b2, e2, NN);

    // ---- Layer 3 ----
    gemm64_kernel<NHID, true><<<GB, 256, 0, stream>>>(e2, W3, tmpb, NN);
    spmm64x_kernel<<<SPMM_GRID, 256, 0, stream>>>(tmpb, row_ptr, pairs, b3, e3, NN);

    // ---- Layer 4 ----
    gemm64_kernel<NHID, true><<<GB, 256, 0, stream>>>(e3, W4, tmpb, NN);
    spmm64x_kernel<<<SPMM_GRID, 256, 0, stream>>>(tmpb, row_ptr, pairs, b4, e4, NN);

    // ---- Layer 5: GEMM (fp32, relu-on-load) -> SpMM fused with log_softmax ----
    gemm_kernel<NHID, NCLASS, 4, true><<<GB, 256, 0, stream>>>(e4, W5, tmp32, NN);
    spmm16_lsm_kernel<<<(NN + 15) / 16, 256, 0, stream>>>(tmp32, row_ptr, pairs, b5, e5, out0, NN);
}

// Round 10
// 344.176 us; speedup vs baseline: 1.1166x; 1.1166x over previous
//
#include <hip/hip_runtime.h>
#include <math.h>

// Problem constants (from reference)
#define NN 50000
#define NE 800000
#define NFEAT 128
#define NHID 64
#define NCLASS 16
#define NB_SCAN ((NN + 255) / 256)  // 196
#define GB ((NN + 63) / 64)         // 782 row-tiles
#define SGRP 4                      // scatter groups (rr re-read SGRP times)
#define ROWS_PER_SGRP ((NN + SGRP - 1) / SGRP)  // 12500
#define SCHUNKS 392                 // scatter chunks per group

// fp32 <-> bf16 helpers (RNE round)
__device__ inline unsigned short f2bf(float f) {
    unsigned u = __builtin_bit_cast(unsigned, f);
    u += 0x7fffu + ((u >> 16) & 1u);
    return (unsigned short)(u >> 16);
}
__device__ inline float bf2f(unsigned short h) {
    return __builtin_bit_cast(float, (unsigned)h << 16);
}
// Packed edge: low 16 = col (NN < 65536), high 16 = weight as bf16.
__device__ inline float pk_w(unsigned v) { return bf2f((unsigned short)(v >> 16)); }
__device__ inline int pk_c(unsigned v) { return (int)(v & 0xffffu); }

// ---------------- CSR build ----------------

// Degree histogram; atomicAdd's return value IS the edge's rank within its row.
__global__ __launch_bounds__(256) void hist_rank_kernel(const int* __restrict__ erow,
                                                        int* __restrict__ deg,
                                                        unsigned* __restrict__ rr, int E) {
    int e = blockIdx.x * 256 + threadIdx.x;
    if (e < E) {
        int r = erow[e];
        int k = atomicAdd(&deg[r], 1);
        rr[e] = ((unsigned)r << 16) | (unsigned)k;
    }
}

__global__ __launch_bounds__(256) void scan_sum_kernel(const int* __restrict__ deg,
                                                       int* __restrict__ blocksum, int n) {
    __shared__ int s[256];
    const int t = threadIdx.x;
    int i = blockIdx.x * 256 + t;
    s[t] = (i < n) ? deg[i] : 0;
    __syncthreads();
#pragma unroll
    for (int off = 128; off > 0; off >>= 1) {
        if (t < off) s[t] += s[t + off];
        __syncthreads();
    }
    if (t == 0) blocksum[blockIdx.x] = s[0];
}

// Merged top-level + final scan: each block scans the 196 block-sums in LDS itself.
__global__ __launch_bounds__(256) void scan_final_kernel(const int* __restrict__ deg,
                                                         const int* __restrict__ blocksum,
                                                         int* __restrict__ row_ptr, int n) {
    __shared__ int bs[256];
    __shared__ int s[256];
    const int t = threadIdx.x;
    bs[t] = (t < NB_SCAN) ? blocksum[t] : 0;
    __syncthreads();
    for (int off = 1; off < 256; off <<= 1) {
        int u = (t >= off) ? bs[t - off] : 0;
        __syncthreads();
        bs[t] += u;
        __syncthreads();
    }
    const int blockpre = (blockIdx.x == 0) ? 0 : bs[blockIdx.x - 1];

    int i = blockIdx.x * 256 + t;
    int d = (i < n) ? deg[i] : 0;
    s[t] = d;
    __syncthreads();
    for (int off = 1; off < 256; off <<= 1) {
        int u = (t >= off) ? s[t - off] : 0;
        __syncthreads();
        s[t] += u;
        __syncthreads();
    }
    int excl = blockpre + s[t] - d;
    if (i < n) {
        row_ptr[i] = excl;
        if (i == n - 1) row_ptr[n] = excl + d;
    }
}

// Atomic-free scatter of 4-byte packed edges: pos = row_ptr[row] + rank.
// 4 destination groups; rr re-read SGRP times (12.8 MB total).
__global__ __launch_bounds__(256) void scatter_rank_kernel(const unsigned* __restrict__ rr,
                                                           const int* __restrict__ ecol,
                                                           const float* __restrict__ ew,
                                                           const int* __restrict__ row_ptr,
                                                           unsigned* __restrict__ pk, int E) {
    const int g = blockIdx.x & (SGRP - 1);
    const int chunk = blockIdx.x / SGRP;
    const int CH = (E + SCHUNKS - 1) / SCHUNKS;
    const int lo = chunk * CH;
    const int hi = (lo + CH < E) ? lo + CH : E;
    for (int e = lo + threadIdx.x; e < hi; e += 256) {
        unsigned v = rr[e];
        int r = (int)(v >> 16);
        if (r / ROWS_PER_SGRP == g) {
            int pos = row_ptr[r] + (int)(v & 0xffffu);
            pk[pos] = ((unsigned)f2bf(ew[e]) << 16) | (unsigned)ecol[e];
        }
    }
}

// ---------------- Tiled GEMM: out[M,64] = act(in[M,K]) @ W[K,64], bf16 out ----------------
template <int K, bool RELU_IN>
__global__ __launch_bounds__(256) void gemm64_kernel(const float* __restrict__ in,
                                                     const float* __restrict__ Wg,
                                                     unsigned short* __restrict__ outb, int M) {
    constexpr int KC = 64;
    __shared__ float xs[KC][68];
    __shared__ float Ws[KC][64];
    const int t = threadIdx.x;
    const int tx = t % 16;
    const int ty = t / 16;
    const int r0 = blockIdx.x * 64;

    float acc[4][4];
#pragma unroll
    for (int i = 0; i < 4; i++)
#pragma unroll
        for (int j = 0; j < 4; j++) acc[i][j] = 0.f;

    for (int k0 = 0; k0 < K; k0 += KC) {
        for (int i = t * 4; i < KC * 64; i += 1024) {
            *(float4*)&Ws[i / 64][i % 64] = *(const float4*)&Wg[(size_t)k0 * 64 + i];
        }
        {
            const int r = t / 4;
            const int q = t % 4;
            const int gr = r0 + r;
#pragma unroll
            for (int i = 0; i < 4; i++) {
                int k = q * 16 + i * 4;
                float4 v;
                if (gr < M)
                    v = *(const float4*)&in[(size_t)gr * K + k0 + k];
                else
                    v = make_float4(0.f, 0.f, 0.f, 0.f);
                if (RELU_IN) {
                    v.x = fmaxf(v.x, 0.f);
                    v.y = fmaxf(v.y, 0.f);
                    v.z = fmaxf(v.z, 0.f);
                    v.w = fmaxf(v.w, 0.f);
                }
                xs[k + 0][r] = v.x;
                xs[k + 1][r] = v.y;
                xs[k + 2][r] = v.z;
                xs[k + 3][r] = v.w;
            }
        }
        __syncthreads();
#pragma unroll 8
        for (int k = 0; k < KC; k++) {
            float4 xv = *(const float4*)&xs[k][ty * 4];
            float4 wv = *(const float4*)&Ws[k][tx * 4];
            acc[0][0] += xv.x * wv.x; acc[0][1] += xv.x * wv.y;
            acc[0][2] += xv.x * wv.z; acc[0][3] += xv.x * wv.w;
            acc[1][0] += xv.y * wv.x; acc[1][1] += xv.y * wv.y;
            acc[1][2] += xv.y * wv.z; acc[1][3] += xv.y * wv.w;
            acc[2][0] += xv.z * wv.x; acc[2][1] += xv.z * wv.y;
            acc[2][2] += xv.z * wv.z; acc[2][3] += xv.z * wv.w;
            acc[3][0] += xv.w * wv.x; acc[3][1] += xv.w * wv.y;
            acc[3][2] += xv.w * wv.z; acc[3][3] += xv.w * wv.w;
        }
        __syncthreads();
    }
#pragma unroll
    for (int i = 0; i < 4; i++) {
        int r = r0 + ty * 4 + i;
        if (r < M) {
            ushort4 u;
            u.x = f2bf(acc[i][0]);
            u.y = f2bf(acc[i][1]);
            u.z = f2bf(acc[i][2]);
            u.w = f2bf(acc[i][3]);
            *(ushort4*)&outb[(size_t)r * 64 + tx * 4] = u;
        }
    }
}

// ---------------- Small GEMM (layer 5): outb16[M,16] = relu(in[M,64]) @ W[64,16] ----------------
template <int K, int NOUT, int RPT, bool RELU_IN>
__global__ __launch_bounds__(256) void gemm16_kernel(const float* __restrict__ in,
                                                     const float* __restrict__ Wg,
                                                     unsigned short* __restrict__ outb, int M) {
    __shared__ float Wl[K * NOUT];
    for (int i = threadIdx.x * 4; i < K * NOUT; i += 256 * 4) {
        *(float4*)&Wl[i] = *(const float4*)&Wg[i];
    }
    __syncthreads();

    constexpr int GROUPS = 256 / NOUT;
    constexpr int RPB = GROUPS * RPT;
    const int col = threadIdx.x % NOUT;
    const int grp = threadIdx.x / NOUT;
    const int r = blockIdx.x * RPB + grp * RPT;
    if (r >= M) return;

    float acc[RPT];
#pragma unroll
    for (int j = 0; j < RPT; j++) acc[j] = 0.f;

    const float* pr = in + (size_t)r * K;
#pragma unroll 2
    for (int k = 0; k < K; k += 4) {
        float w0 = Wl[(k + 0) * NOUT + col];
        float w1 = Wl[(k + 1) * NOUT + col];
        float w2 = Wl[(k + 2) * NOUT + col];
        float w3 = Wl[(k + 3) * NOUT + col];
#pragma unroll
        for (int j = 0; j < RPT; j++) {
            float4 xv = *(const float4*)(pr + j * K + k);
            if (RELU_IN) {
                xv.x = fmaxf(xv.x, 0.f);
                xv.y = fmaxf(xv.y, 0.f);
                xv.z = fmaxf(xv.z, 0.f);
                xv.w = fmaxf(xv.w, 0.f);
            }
            acc[j] += xv.x * w0;
            acc[j] += xv.y * w1;
            acc[j] += xv.z * w2;
            acc[j] += xv.w * w3;
        }
    }
#pragma unroll
    for (int j = 0; j < RPT; j++) {
        if (r + j < M) outb[(size_t)(r + j) * NOUT + col] = f2bf(acc[j]);
    }
}

// ---------------- SpMM (F=64, bf16 gather, packed 4B edges) ----------------
// 2 rows per wave (32 lanes/row), lane loads a ushort2 feature-pair, unroll-8.
__global__ __launch_bounds__(256) void spmm64v2_kernel(const unsigned short* __restrict__ tmpb,
                                                       const int* __restrict__ row_ptr,
                                                       const unsigned* __restrict__ pk,
                                                       const float* __restrict__ bias,
                                                       float* __restrict__ e_out, int M) {
    const int t = threadIdx.x;
    const int r = blockIdx.x * 8 + (t >> 5);
    if (r >= M) return;
    const int f2 = (t & 31) * 2;

    int e = row_ptr[r];
    const int end = row_ptr[r + 1];
    float a0 = 0.f, a1 = 0.f;
    for (; e + 7 < end; e += 8) {
        unsigned q0 = pk[e + 0], q1 = pk[e + 1], q2 = pk[e + 2], q3 = pk[e + 3];
        unsigned q4 = pk[e + 4], q5 = pk[e + 5], q6 = pk[e + 6], q7 = pk[e + 7];
        unsigned g0 = *(const unsigned*)&tmpb[(size_t)pk_c(q0) * 64 + f2];
        unsigned g1 = *(const unsigned*)&tmpb[(size_t)pk_c(q1) * 64 + f2];
        unsigned g2 = *(const unsigned*)&tmpb[(size_t)pk_c(q2) * 64 + f2];
        unsigned g3 = *(const unsigned*)&tmpb[(size_t)pk_c(q3) * 64 + f2];
        unsigned g4 = *(const unsigned*)&tmpb[(size_t)pk_c(q4) * 64 + f2];
        unsigned g5 = *(const unsigned*)&tmpb[(size_t)pk_c(q5) * 64 + f2];
        unsigned g6 = *(const unsigned*)&tmpb[(size_t)pk_c(q6) * 64 + f2];
        unsigned g7 = *(const unsigned*)&tmpb[(size_t)pk_c(q7) * 64 + f2];
        a0 += pk_w(q0) * bf2f((unsigned short)(g0 & 0xffffu));
        a1 += pk_w(q0) * bf2f((unsigned short)(g0 >> 16));
        a0 += pk_w(q1) * bf2f((unsigned short)(g1 & 0xffffu));
        a1 += pk_w(q1) * bf2f((unsigned short)(g1 >> 16));
        a0 += pk_w(q2) * bf2f((unsigned short)(g2 & 0xffffu));
        a1 += pk_w(q2) * bf2f((unsigned short)(g2 >> 16));
        a0 += pk_w(q3) * bf2f((unsigned short)(g3 & 0xffffu));
        a1 += pk_w(q3) * bf2f((unsigned short)(g3 >> 16));
        a0 += pk_w(q4) * bf2f((unsigned short)(g4 & 0xffffu));
        a1 += pk_w(q4) * bf2f((unsigned short)(g4 >> 16));
        a0 += pk_w(q5) * bf2f((unsigned short)(g5 & 0xffffu));
        a1 += pk_w(q5) * bf2f((unsigned short)(g5 >> 16));
        a0 += pk_w(q6) * bf2f((unsigned short)(g6 & 0xffffu));
        a1 += pk_w(q6) * bf2f((unsigned short)(g6 >> 16));
        a0 += pk_w(q7) * bf2f((unsigned short)(g7 & 0xffffu));
        a1 += pk_w(q7) * bf2f((unsigned short)(g7 >> 16));
    }
    for (; e < end; e++) {
        unsigned q = pk[e];
        unsigned g = *(const unsigned*)&tmpb[(size_t)pk_c(q) * 64 + f2];
        a0 += pk_w(q) * bf2f((unsigned short)(g & 0xffffu));
        a1 += pk_w(q) * bf2f((unsigned short)(g >> 16));
    }
    float2 v;
    v.x = a0 + bias[f2];
    v.y = a1 + bias[f2 + 1];
    *(float2*)&e_out[(size_t)r * 64 + f2] = v;
}

// ---------------- SpMM (F=16, bf16 gather, packed edges) fused with log_softmax ----------------
__global__ __launch_bounds__(256) void spmm16_lsm_kernel(const unsigned short* __restrict__ tmpc,
                                                         const int* __restrict__ row_ptr,
                                                         const unsigned* __restrict__ pk,
                                                         const float* __restrict__ bias,
                                                         float* __restrict__ e5,
                                                         float* __restrict__ out0, int M) {
    const int f = threadIdx.x & 15;
    const int rl = threadIdx.x >> 4;
    const int r = blockIdx.x * 16 + rl;
    if (r >= M) return;

    int e = row_ptr[r];
    const int end = row_ptr[r + 1];
    float acc = 0.f;
    for (; e + 7 < end; e += 8) {
        unsigned q0 = pk[e + 0], q1 = pk[e + 1], q2 = pk[e + 2], q3 = pk[e + 3];
        unsigned q4 = pk[e + 4], q5 = pk[e + 5], q6 = pk[e + 6], q7 = pk[e + 7];
        acc += pk_w(q0) * bf2f(tmpc[(size_t)pk_c(q0) * 16 + f]);
        acc += pk_w(q1) * bf2f(tmpc[(size_t)pk_c(q1) * 16 + f]);
        acc += pk_w(q2) * bf2f(tmpc[(size_t)pk_c(q2) * 16 + f]);
        acc += pk_w(q3) * bf2f(tmpc[(size_t)pk_c(q3) * 16 + f]);
        acc += pk_w(q4) * bf2f(tmpc[(size_t)pk_c(q4) * 16 + f]);
        acc += pk_w(q5) * bf2f(tmpc[(size_t)pk_c(q5) * 16 + f]);
        acc += pk_w(q6) * bf2f(tmpc[(size_t)pk_c(q6) * 16 + f]);
        acc += pk_w(q7) * bf2f(tmpc[(size_t)pk_c(q7) * 16 + f]);
    }
    for (; e < end; e++) {
        unsigned q = pk[e];
        acc += pk_w(q) * bf2f(tmpc[(size_t)pk_c(q) * 16 + f]);
    }
    float v = acc + bias[f];
    e5[(size_t)r * 16 + f] = v;

    float m = v;
#pragma unroll
    for (int off = 1; off < 16; off <<= 1) m = fmaxf(m, __shfl_xor(m, off, 16));
    float s = expf(v - m);
#pragma unroll
    for (int off = 1; off < 16; off <<= 1) s += __shfl_xor(s, off, 16);
    float ls = logf(s);
    out0[(size_t)r * 16 + f] = v - m - ls;
}

// ---------------- launch ----------------

extern "C" void kernel_launch(void* const* d_in, const int* in_sizes, int n_in,
                              void* d_out, int out_size, void* d_ws, size_t ws_size,
                              hipStream_t stream) {
    const float* x = (const float*)d_in[0];
    const int* erow = (const int*)d_in[1];
    const int* ecol = (const int*)d_in[2];
    const float* ew = (const float*)d_in[3];
    const float* W1 = (const float*)d_in[4];
    const float* b1 = (const float*)d_in[5];
    const float* W2 = (const float*)d_in[6];
    const float* b2 = (const float*)d_in[7];
    const float* W3 = (const float*)d_in[8];
    const float* b3 = (const float*)d_in[9];
    const float* W4 = (const float*)d_in[10];
    const float* b4 = (const float*)d_in[11];
    const float* W5 = (const float*)d_in[12];
    const float* b5 = (const float*)d_in[13];

    // Output layout: log_softmax(e5), e1, e2, e3, e4, e5
    float* out0 = (float*)d_out;
    float* e1 = out0 + (size_t)NN * NCLASS;
    float* e2 = e1 + (size_t)NN * NHID;
    float* e3 = e2 + (size_t)NN * NHID;
    float* e4 = e3 + (size_t)NN * NHID;
    float* e5 = e4 + (size_t)NN * NHID;

    // Workspace layout
    char* ws = (char*)d_ws;
    unsigned short* tmpb = (unsigned short*)ws; ws += (size_t)NN * NHID * 2;   // 6.4 MB
    unsigned short* tmpc = (unsigned short*)ws; ws += ((size_t)NN * NCLASS * 2 + 255) / 256 * 256;  // 1.6 MB
    int* deg = (int*)ws;       ws += ((size_t)NN * 4 + 255) / 256 * 256;       // zeroed below
    int* row_ptr = (int*)ws;   ws += ((size_t)(NN + 1) * 4 + 255) / 256 * 256;
    int* blocksum = (int*)ws;  ws += ((size_t)NB_SCAN * 4 + 255) / 256 * 256;
    unsigned* rr = (unsigned*)ws; ws += (size_t)NE * 4;                        // 3.2 MB
    unsigned* pk = (unsigned*)ws; ws += (size_t)NE * 4;                        // 3.2 MB packed edges

    // ---- CSR build: hist+rank, scans (merged), atomic-free partitioned scatter ----
    hipMemsetAsync(deg, 0, (size_t)NN * 4, stream);
    hist_rank_kernel<<<(NE + 255) / 256, 256, 0, stream>>>(erow, deg, rr, NE);
    scan_sum_kernel<<<NB_SCAN, 256, 0, stream>>>(deg, blocksum, NN);
    scan_final_kernel<<<NB_SCAN, 256, 0, stream>>>(deg, blocksum, row_ptr, NN);
    scatter_rank_kernel<<<SGRP * SCHUNKS, 256, 0, stream>>>(rr, ecol, ew, row_ptr, pk, NE);

    // ---- Layer 1 ----
    gemm64_kernel<NFEAT, false><<<GB, 256, 0, stream>>>(x, W1, tmpb, NN);
    spmm64v2_kernel<<<(NN + 7) / 8, 256, 0, stream>>>(tmpb, row_ptr, pk, b1, e1, NN);

    // ---- Layer 2 (reads e1 with relu-on-load) ----
    gemm64_kernel<NHID, true><<<GB, 256, 0, stream>>>(e1, W2, tmpb, NN);
    spmm64v2_kernel<<<(NN + 7) / 8, 256, 0, stream>>>(tmpb, row_ptr, pk, b2, e2, NN);

    // ---- Layer 3 ----
    gemm64_kernel<NHID, true><<<GB, 256, 0, stream>>>(e2, W3, tmpb, NN);
    spmm64v2_kernel<<<(NN + 7) / 8, 256, 0, stream>>>(tmpb, row_ptr, pk, b3, e3, NN);

    // ---- Layer 4 ----
    gemm64_kernel<NHID, true><<<GB, 256, 0, stream>>>(e3, W4, tmpb, NN);
    spmm64v2_kernel<<<(NN + 7) / 8, 256, 0, stream>>>(tmpb, row_ptr, pk, b4, e4, NN);

    // ---- Layer 5: GEMM (bf16 out, relu-on-load) -> SpMM fused with log_softmax ----
    gemm16_kernel<NHID, NCLASS, 4, true><<<GB, 256, 0, stream>>>(e4, W5, tmpc, NN);
    spmm16_lsm_kernel<<<(NN + 15) / 16, 256, 0, stream>>>(tmpc, row_ptr, pk, b5, e5, out0, NN);
}